// Round 8
// baseline (163.694 us; speedup 1.0000x reference)
//
#include <hip/hip_runtime.h>
#include <math.h>

#define ALPHA   0.99f
#define ONE_M   0.01f     // 1 - ALPHA
#define T_LEN   4000
#define F_DIM   64
#define TT      250       // time steps per tile
#define NTILE   16        // T_LEN / TT
#define LT      5         // elements per thread per tile
#define NC      50        // chunks per tile = TT / LT
#define NTHREADS (NC * 16)   // 800

typedef float f32x4 __attribute__((ext_vector_type(4)));

// Volatile asm loads/stores: deterministic vmcnt counts, cannot be sunk.
#define GLD5(B, P)                                                          \
  asm volatile("global_load_dwordx4 %0, %5, off\n\t"                        \
               "global_load_dwordx4 %1, %5, off offset:256\n\t"             \
               "global_load_dwordx4 %2, %5, off offset:512\n\t"             \
               "global_load_dwordx4 %3, %5, off offset:768\n\t"             \
               "global_load_dwordx4 %4, %5, off offset:1024"                \
               : "=&v"((B)[0]), "=&v"((B)[1]), "=&v"((B)[2]),               \
                 "=&v"((B)[3]), "=&v"((B)[4])                               \
               : "v"(P) : "memory")

#define GST5(P, O)                                                          \
  asm volatile("global_store_dwordx4 %5, %0, off\n\t"                       \
               "global_store_dwordx4 %5, %1, off offset:256\n\t"            \
               "global_store_dwordx4 %5, %2, off offset:512\n\t"            \
               "global_store_dwordx4 %5, %3, off offset:768\n\t"            \
               "global_store_dwordx4 %5, %4, off offset:1024"               \
               :: "v"((O)[0]), "v"((O)[1]), "v"((O)[2]), "v"((O)[3]),       \
                  "v"((O)[4]), "v"(P) : "memory")

#define WAITV(n)                                                            \
  do { asm volatile("s_waitcnt vmcnt(" #n ")" ::: "memory");                \
       __builtin_amdgcn_sched_barrier(0); } while (0)

// Pin store-data buffers live: outstanding asm stores read these VGPRs after
// the GST5 "completes" at C level; without this the allocator reuses them.
#define KEEP_O()                                                            \
  asm volatile("" :: "v"(oA[0]), "v"(oA[1]), "v"(oA[2]), "v"(oA[3]),        \
                     "v"(oA[4]), "v"(oB[0]), "v"(oB[1]), "v"(oB[2]),        \
                     "v"(oB[3]), "v"(oB[4]))

// lgkmcnt(0) + raw s_barrier: LDS visibility WITHOUT draining vmcnt, so the
// next-tile global loads (and prior-tile stores) stay in flight across it.
#define LGKM_BAR()                                                          \
  do { asm volatile("s_waitcnt lgkmcnt(0)" ::: "memory");                   \
       __builtin_amdgcn_sched_barrier(0);                                   \
       __builtin_amdgcn_s_barrier();                                        \
       __builtin_amdgcn_sched_barrier(0); } while (0)

// One tile: prefetch next tile into VB, pass-1 on VA (in registers),
// combine (wave 0), pass-2 replay from the SAME registers, store via OO.
// vmcnt trace (steady state): enter=[5 st(k-1)]; +5 ld(k+1); +5 st(k);
// WAITV(5) drains st(k-1)+ld(k+1), leaves st(k) -> OO's twin reusable next.
#define TILE_BODY(VA, VB, OO, kk)                                           \
  {                                                                         \
    const int kn = ((kk) + 1 < NTILE) ? (kk) + 1 : (kk);                    \
    GLD5(VB, xbase + (size_t)kn * TT * F_DIM);                              \
    f32x4 m = 0.f, sp = 0.f, su = 0.f;                                      \
    _Pragma("unroll")                                                       \
    for (int j = 0; j < LT; ++j) {                                          \
      f32x4 xi = VA[j];                                                     \
      m = ALPHA * m + ONE_M * xi;                                           \
      f32x4 u = xi - m;                                                     \
      sp = ALPHA * sp + ONE_M * (u * u);                                    \
      su = su + u;                                                          \
    }                                                                       \
    *(f32x4*)&s_m [c][g * 4] = m;                                           \
    *(f32x4*)&s_sp[c][g * 4] = sp;                                          \
    *(f32x4*)&s_su[c][g * 4] = su;                                          \
    LGKM_BAR();                                                             \
    if (tid < F_DIM) {                                                      \
      float mu = cmu, var = cvar;                                           \
      for (int cc = 0; cc < NC; ++cc) {                                     \
        float mm = s_m[cc][tid], pp = s_sp[cc][tid], uu = s_su[cc][tid];    \
        s_m [cc][tid] = mu;                                                 \
        s_sp[cc][tid] = var;                                                \
        float mun = AL * mu + mm;                                           \
        var = AL * var + pp + (C2 * uu) * mu + RR * mu * mu;                \
        mu = mun;                                                           \
      }                                                                     \
      cmu = mu; cvar = var;                                                 \
    }                                                                       \
    LGKM_BAR();                                                             \
    f32x4 mu2  = *(f32x4*)&s_m [c][g * 4];                                  \
    f32x4 var2 = *(f32x4*)&s_sp[c][g * 4];                                  \
    LGKM_BAR();   /* entering-state reads done -> arrays reusable */        \
    _Pragma("unroll")                                                       \
    for (int j = 0; j < LT; ++j) {                                          \
      f32x4 xi = VA[j];                                                     \
      mu2 = ALPHA * mu2 + ONE_M * xi;                                       \
      f32x4 d = xi - mu2;                                                   \
      var2 = ALPHA * var2 + ONE_M * (d * d);                                \
      OO[j][0] = d[0] * __builtin_amdgcn_rsqf(var2[0]);                     \
      OO[j][1] = d[1] * __builtin_amdgcn_rsqf(var2[1]);                     \
      OO[j][2] = d[2] * __builtin_amdgcn_rsqf(var2[2]);                     \
      OO[j][3] = d[3] * __builtin_amdgcn_rsqf(var2[3]);                     \
    }                                                                       \
    GST5(obase + (size_t)(kk) * TT * F_DIM, OO);                            \
    WAITV(5);                                                               \
    KEEP_O();                                                               \
  }

// Exact chunked scan, per (b, f):
//   mu_L  = a^L mu_0 + m_L
//   var_L = a^L var_0 + SP + c2*SU*mu_0 + R*mu_0^2
// x is read from HBM exactly ONCE: each thread holds its LT=5 float4
// elements in registers across pass-1 / combine / pass-2. No vmcnt(0)
// drain anywhere in the tile loop.
__global__ __launch_bounds__(NTHREADS, 2)
void erbnorm_kernel(const float* __restrict__ x, float* __restrict__ out, float aL) {
    const int b   = blockIdx.x;
    const int tid = threadIdx.x;
    const int c   = tid >> 4;          // chunk within tile 0..49
    const int g   = tid & 15;          // float4 group 0..15

    const float AL = aL;
    const float C2 = -2.f * ONE_M * aL;        // -2(1-a)a^L
    const float RR = ALPHA * aL * (1.f - aL);  // a^(L+1)(1-a^L)

    __shared__ float s_m [NC][F_DIM];
    __shared__ float s_sp[NC][F_DIM];
    __shared__ float s_su[NC][F_DIM];

    const size_t goff = ((size_t)b * T_LEN + (size_t)c * LT) * F_DIM + g * 4;
    const float* xbase = x   + goff;
    float*       obase = out + goff;

    // combine-chain state (meaningful for tid < 64)
    float cmu  = -60.f + (float)tid * (-30.f / 63.f);
    float cvar = 1600.f;

    f32x4 vA[LT], vB[LT];
    f32x4 oA[LT], oB[LT];
#pragma unroll
    for (int j = 0; j < LT; ++j) { oA[j] = 0.f; oB[j] = 0.f; }

    GLD5(vA, xbase);
    WAITV(0);

    for (int k2 = 0; k2 < NTILE; k2 += 2) {
        TILE_BODY(vA, vB, oA, k2);
        TILE_BODY(vB, vA, oB, k2 + 1);
    }
}

extern "C" void kernel_launch(void* const* d_in, const int* in_sizes, int n_in,
                              void* d_out, int out_size, void* d_ws, size_t ws_size,
                              hipStream_t stream) {
    const float* x = (const float*)d_in[0];
    float* out = (float*)d_out;
    const float aL = (float)pow(0.99, (double)LT);  // a^5
    hipLaunchKernelGGL(erbnorm_kernel, dim3(256), dim3(NTHREADS), 0, stream,
                       x, out, aL);
}

// Round 10
// 110.418 us; speedup vs baseline: 1.4825x; 1.4825x over previous
//
#include <hip/hip_runtime.h>
#include <math.h>

#define ALPHA   0.99f
#define ONE_M   0.01f     // 1 - ALPHA
#define T_LEN   4000
#define F_DIM   64
#define TT      160       // time rows per tile
#define NTILE   25        // T_LEN / TT
#define LTC     5         // chunk length (rows per chunk)
#define NC      32        // chunks per tile = TT / LTC
#define NPC     5         // coop pieces per thread = TT*F_DIM/(NTHREADS*4)
#define NTHREADS 512      // 8 waves exactly
#define ROWF    68        // LDS image row stride in floats (272 B, 16B-aligned rows)

typedef float f32x4 __attribute__((ext_vector_type(4)));

// Barrier WITHOUT vmcnt drain: LDS visibility only. Global loads/stores
// (compiler-generated, lifetimes compiler-tracked) stay in flight across it.
#define LGKM_BAR()                                                    \
  do { asm volatile("s_waitcnt lgkmcnt(0)" ::: "memory");             \
       __builtin_amdgcn_sched_barrier(0);                             \
       __builtin_amdgcn_s_barrier();                                  \
       __builtin_amdgcn_sched_barrier(0); } while (0)

// One tile. VC holds tile kk's coop-linear pieces; VN receives tile kk+1's.
// All global traffic is coop-linear: lane i <-> bytes [16i,16i+16) of a
// contiguous 2 KB-per-wave... (64 lanes x 16 B = 1 KB contiguous per instr).
#define TILE_BODY(VC, VN, kk)                                               \
  {                                                                         \
    const size_t tb = bbase + (size_t)(kk) * TT * F_DIM;                    \
    /* P1: coop-linear pieces -> image (row t = r*NC + c) */                \
    _Pragma("unroll")                                                       \
    for (int r = 0; r < NPC; ++r) {                                         \
      const int t = r * NC + c;                                             \
      *(f32x4*)&s_img[t * ROWF + g * 4] = VC[r];                            \
    }                                                                       \
    LGKM_BAR();                                                             \
    /* P2: chunk-layout reads; issue next tile's loads; pass-1; summaries */\
    f32x4 vX[LTC];                                                          \
    _Pragma("unroll")                                                       \
    for (int j = 0; j < LTC; ++j)                                           \
      vX[j] = *(const f32x4*)&s_img[(LTC * c + j) * ROWF + g * 4];          \
    if ((kk) + 1 < NTILE) {                                                 \
      _Pragma("unroll")                                                     \
      for (int r = 0; r < NPC; ++r)                                         \
        VN[r] = *(const f32x4*)(x + tb + (size_t)TT * F_DIM                 \
                                + (size_t)tid * 4 + (size_t)r * 2048);      \
    }                                                                       \
    f32x4 m = 0.f, sp = 0.f, su = 0.f;                                      \
    _Pragma("unroll")                                                       \
    for (int j = 0; j < LTC; ++j) {                                         \
      f32x4 xi = vX[j];                                                     \
      m = ALPHA * m + ONE_M * xi;                                           \
      f32x4 u = xi - m;                                                     \
      sp = ALPHA * sp + ONE_M * (u * u);                                    \
      su = su + u;                                                          \
    }                                                                       \
    *(f32x4*)&s_m [c * F_DIM + g * 4] = m;                                  \
    *(f32x4*)&s_sp[c * F_DIM + g * 4] = sp;                                 \
    *(f32x4*)&s_su[c * F_DIM + g * 4] = su;                                 \
    LGKM_BAR();                                                             \
    /* P3: combine — serial chain over NC chunks, wave-0 threads 0..63 */   \
    if (tid < F_DIM) {                                                      \
      float mu = cmu, var = cvar;                                           \
      for (int cc = 0; cc < NC; ++cc) {                                     \
        float mm = s_m [cc * F_DIM + tid];                                  \
        float pp = s_sp[cc * F_DIM + tid];                                  \
        float uu = s_su[cc * F_DIM + tid];                                  \
        s_m [cc * F_DIM + tid] = mu;          /* entering state */          \
        s_sp[cc * F_DIM + tid] = var;                                       \
        float mun = AL * mu + mm;                                           \
        var = AL * var + pp + (C2 * uu) * mu + RR * mu * mu;                \
        mu = mun;                                                           \
      }                                                                     \
      cmu = mu; cvar = var;                                                 \
    }                                                                       \
    LGKM_BAR();                                                             \
    /* P4: entering state; pass-2 replay; output into image (chunk rows) */ \
    f32x4 mu2  = *(const f32x4*)&s_m [c * F_DIM + g * 4];                   \
    f32x4 var2 = *(const f32x4*)&s_sp[c * F_DIM + g * 4];                   \
    _Pragma("unroll")                                                       \
    for (int j = 0; j < LTC; ++j) {                                         \
      f32x4 xi = vX[j];                                                     \
      mu2 = ALPHA * mu2 + ONE_M * xi;                                       \
      f32x4 d = xi - mu2;                                                   \
      var2 = ALPHA * var2 + ONE_M * (d * d);                                \
      f32x4 o;                                                              \
      o[0] = d[0] * __builtin_amdgcn_rsqf(var2[0]);                         \
      o[1] = d[1] * __builtin_amdgcn_rsqf(var2[1]);                         \
      o[2] = d[2] * __builtin_amdgcn_rsqf(var2[2]);                         \
      o[3] = d[3] * __builtin_amdgcn_rsqf(var2[3]);                         \
      *(f32x4*)&s_img[(LTC * c + j) * ROWF + g * 4] = o;                    \
    }                                                                       \
    LGKM_BAR();                                                             \
    /* P5: coop-linear read-back + contiguous 1KB-per-wave stores */        \
    _Pragma("unroll")                                                       \
    for (int r = 0; r < NPC; ++r) {                                         \
      const int t = r * NC + c;                                             \
      f32x4 oc = *(const f32x4*)&s_img[t * ROWF + g * 4];                   \
      *(f32x4*)(out + tb + (size_t)tid * 4 + (size_t)r * 2048) = oc;        \
    }                                                                       \
    LGKM_BAR();  /* image reads done before next tile overwrites */         \
  }

// Exact chunked scan per (b,f):
//   mu_L  = a^L mu_0 + m_L
//   var_L = a^L var_0 + SP + c2*SU*mu_0 + R*mu_0^2  (L = LTC = 5)
// x read from HBM exactly once. LDS image (padded rows) transposes
// coop-linear <-> chunk layout in both directions, so every global wave
// instruction touches one contiguous aligned 1 KB segment.
__global__ __launch_bounds__(NTHREADS, 2)
void erbnorm_kernel(const float* __restrict__ x, float* __restrict__ out, float aL) {
    const int b   = blockIdx.x;
    const int tid = threadIdx.x;
    const int c   = tid >> 4;          // chunk 0..31 (== coop row sub-index)
    const int g   = tid & 15;          // float4 group 0..15

    const float AL = aL;
    const float C2 = -2.f * ONE_M * aL;        // -2(1-a)a^L
    const float RR = ALPHA * aL * (1.f - aL);  // a^(L+1)(1-a^L)

    __shared__ __align__(16) float s_img[TT * ROWF];          // 43,520 B
    __shared__ float s_m [NC * F_DIM];                        //  8,192 B
    __shared__ float s_sp[NC * F_DIM];                        //  8,192 B
    __shared__ float s_su[NC * F_DIM];                        //  8,192 B

    const size_t bbase = (size_t)b * T_LEN * F_DIM;

    // combine-chain state (meaningful for tid < 64)
    float cmu  = -60.f + (float)tid * (-30.f / 63.f);
    float cvar = 1600.f;

    f32x4 vA[NPC], vB[NPC];
    // prologue: tile 0, coop-linear
#pragma unroll
    for (int r = 0; r < NPC; ++r)
        vA[r] = *(const f32x4*)(x + bbase + (size_t)tid * 4 + (size_t)r * 2048);

    for (int k2 = 0; k2 < NTILE - 1; k2 += 2) {   // 12 pairs: tiles 0..23
        TILE_BODY(vA, vB, k2);
        TILE_BODY(vB, vA, k2 + 1);
    }
    TILE_BODY(vA, vB, NTILE - 1);                 // tail tile 24 (no prefetch)
}

extern "C" void kernel_launch(void* const* d_in, const int* in_sizes, int n_in,
                              void* d_out, int out_size, void* d_ws, size_t ws_size,
                              hipStream_t stream) {
    const float* x = (const float*)d_in[0];
    float* out = (float*)d_out;
    const float aL = (float)pow(0.99, (double)LTC);  // a^5
    hipLaunchKernelGGL(erbnorm_kernel, dim3(256), dim3(NTHREADS), 0, stream,
                       x, out, aL);
}